// Round 8
// baseline (277.134 us; speedup 1.0000x reference)
//
#include <hip/hip_runtime.h>
#include <hip/hip_bf16.h>
#include <math.h>

#define NXC 4096
#define NNODES 32768       // B*NX = 8*4096

typedef __attribute__((ext_vector_type(8))) short bf16x8;
typedef __attribute__((ext_vector_type(4))) short s16x4;
typedef __attribute__((ext_vector_type(16))) float f32x16;
typedef __attribute__((ext_vector_type(2))) float f32x2;

#define MFMA32(a,b,c) __builtin_amdgcn_mfma_f32_32x32x16_bf16((a),(b),(c),0,0,0)

// ---- transcendental-free GELU (quartic erf fit, |err| ~5e-3, under bf16 grid) ----
#define GC4  3.359256e-5f
#define GC3 -0.000850511f
#define GC2  0.00941855f
#define GC1 -0.06622291f
#define GC0  0.3989423f

__device__ __forceinline__ float gelu_f(float x) {
    float xc = fminf(fmaxf(x, -3.0f), 3.0f);
    float s = xc * xc;
    float q = fmaf(s, GC4, GC3);
    q = fmaf(s, q, GC2);
    q = fmaf(s, q, GC1);
    q = fmaf(s, q, GC0);
    return x * fmaf(xc, q, 0.5f);
}
__device__ __forceinline__ f32x2 gelu2(f32x2 x) {
    const f32x2 lo = {-3.0f, -3.0f}, hi = {3.0f, 3.0f};
    const f32x2 c4 = {GC4, GC4}, c3 = {GC3, GC3}, c2 = {GC2, GC2};
    const f32x2 c1 = {GC1, GC1}, c0 = {GC0, GC0}, half = {0.5f, 0.5f};
    f32x2 xc = __builtin_elementwise_min(__builtin_elementwise_max(x, lo), hi);
    f32x2 s = xc * xc;
    f32x2 q = __builtin_elementwise_fma(s, c4, c3);
    q = __builtin_elementwise_fma(s, q, c2);
    q = __builtin_elementwise_fma(s, q, c1);
    q = __builtin_elementwise_fma(s, q, c0);
    return x * __builtin_elementwise_fma(xc, q, half);
}
__device__ __forceinline__ float sigmoid_f(float v) {
    float e = __builtin_amdgcn_exp2f(-1.4426950409f * v);
    return __builtin_amdgcn_rcpf(1.0f + e);
}
__device__ __forceinline__ short f2bs(float x) {
    __hip_bfloat16 b = __float2bfloat16(x);
    union { __hip_bfloat16 h; short s; } u; u.h = b; return u.s;
}
__device__ __forceinline__ f32x16 zero16() {
    f32x16 v;
    #pragma unroll
    for (int i = 0; i < 16; ++i) v[i] = 0.f;
    return v;
}
__device__ __forceinline__ float dpp_xor1(float x) {
    return __int_as_float(__builtin_amdgcn_update_dpp(0, __float_as_int(x), 0xB1, 0xF, 0xF, true));
}
__device__ __forceinline__ float dpp_xor2(float x) {
    return __int_as_float(__builtin_amdgcn_update_dpp(0, __float_as_int(x), 0x4E, 0xF, 0xF, true));
}

// ---------------- weight prep + tau terms (fused) ----------------
__global__ void wconv_kernel(const float* __restrict__ msg_w2, const float* __restrict__ msg_w3,
                             const float* __restrict__ msg_w1, const float* __restrict__ gate_w1,
                             const float* __restrict__ upd_w1, const float* __restrict__ upd_w2,
                             const float* __restrict__ upd_w3, const float* __restrict__ W_w,
                             const float* __restrict__ tau,
                             const float* __restrict__ msg_b1, const float* __restrict__ gate_b1,
                             const float* __restrict__ upd_b1,
                             __hip_bfloat16* __restrict__ w2t, __hip_bfloat16* __restrict__ w3t,
                             __hip_bfloat16* __restrict__ wall_t, __hip_bfloat16* __restrict__ w1ut,
                             __hip_bfloat16* __restrict__ w2ut, __hip_bfloat16* __restrict__ w3ut,
                             __hip_bfloat16* __restrict__ wwt,
                             float* __restrict__ TM, float* __restrict__ TG, float* __restrict__ TU)
{
    if (blockIdx.x >= 1600) {   // tau terms for batch b
        const int b = blockIdx.x - 1600;   // 0..7
        const int t = threadIdx.x;
        float tv[16];
        #pragma unroll
        for (int k = 0; k < 16; ++k) tv[k] = tau[b*16 + k];
        float am = msg_b1[t], ag = gate_b1[t], au = upd_b1[t];
        #pragma unroll
        for (int k = 0; k < 16; ++k) {
            am = fmaf(tv[k], msg_w1 [(257+k)*256 + t], am);
            ag = fmaf(tv[k], gate_w1[(257+k)*256 + t], ag);
            au = fmaf(tv[k], upd_w1 [(256+k)*256 + t], au);
        }
        TM[b*256+t] = am; TG[b*256+t] = ag; TU[b*256+t] = au;
        return;
    }
    int i = blockIdx.x * 256 + threadIdx.x;   // 0 .. 409599
    if (i < 65536) { int c=i>>8, k=i&255; w2t[i] = __float2bfloat16(msg_w2[k*256+c]); return; }
    i -= 65536;
    if (i < 32768) { int c=i>>8, k=i&255; w3t[i] = __float2bfloat16(msg_w3[k*128+c]); return; }
    i -= 32768;
    if (i < 131072) {
        int c = i>>7, k = i&127; float v;
        if      (c <  256) v = msg_w1 [k*256 + c];
        else if (c <  512) v = msg_w1 [(128+k)*256 + (c-256)];
        else if (c <  768) v = gate_w1[k*256 + (c-512)];
        else               v = gate_w1[(128+k)*256 + (c-768)];
        wall_t[i] = __float2bfloat16(v); return;
    }
    i -= 131072;
    if (i < 65536) { int c=i>>8, k=i&255; w1ut[i] = __float2bfloat16(upd_w1[k*256+c]); return; }
    i -= 65536;
    if (i < 65536) { int c=i>>8, k=i&255; w2ut[i] = __float2bfloat16(upd_w2[k*256+c]); return; }
    i -= 65536;
    if (i < 32768) { int c=i>>8, k=i&255; w3ut[i] = __float2bfloat16(upd_w3[k*128+c]); return; }
    i -= 32768;
    { int c=i>>7, k=i&127; wwt[i] = __float2bfloat16(W_w[k*128+c]); }
}

// ---------------- per-node precompute (MFMA, 512 thr): [PAm|PBm|PAg|PBg] = h @ wall ----------------
#define PSTR 136   // h-tile LDS row stride (bf16), 272 B

__global__ __launch_bounds__(512, 6)
void precompute_kernel(const float* __restrict__ h, const __hip_bfloat16* __restrict__ wall_t,
                       __hip_bfloat16* __restrict__ PAm, __hip_bfloat16* __restrict__ PBm,
                       __hip_bfloat16* __restrict__ PAg, __hip_bfloat16* __restrict__ PBg)
{
    __shared__ __align__(16) __hip_bfloat16 hs[64*PSTR];   // 17.4 KB
    __shared__ __align__(16) __hip_bfloat16 ob[64*256];    // 32.8 KB
    const int t = threadIdx.x;          // 0..511
    const int lane = t & 63, wv = t >> 6;
    const int cl = lane & 31, g = lane >> 5;
    const int base = blockIdx.x * 64;

    #pragma unroll
    for (int i = 0; i < 4; ++i) {          // stage h tile (64x128 f32 -> bf16)
        int f = (i*512 + t)*4;
        float4 hv = *(const float4*)&h[(size_t)base*128 + f];
        int row = f >> 7, col = f & 127;
        s16x4 pk; pk[0]=f2bs(hv.x); pk[1]=f2bs(hv.y); pk[2]=f2bs(hv.z); pk[3]=f2bs(hv.w);
        *(s16x4*)&hs[row*PSTR + col] = pk;
    }
    __syncthreads();

    __hip_bfloat16* bufs[4] = {PAm, PBm, PAg, PBg};
    const int c0 = wv*32 + cl;
    const __hip_bfloat16* a0  = hs + (size_t)(cl)*PSTR + g*8;
    const __hip_bfloat16* a1p = hs + (size_t)(32+cl)*PSTR + g*8;

    for (int tile = 0; tile < 4; ++tile) {
        f32x16 acc0 = zero16(), acc1 = zero16();
        {
            const __hip_bfloat16* b0 = wall_t + ((size_t)tile*256 + c0)*128 + g*8;
            #pragma unroll
            for (int kt = 0; kt < 8; ++kt) {
                bf16x8 bf = *(const bf16x8*)(b0 + kt*16);
                acc0 = MFMA32(*(const bf16x8*)(a0  + kt*16), bf, acc0);
                acc1 = MFMA32(*(const bf16x8*)(a1p + kt*16), bf, acc1);
            }
        }
        #pragma unroll
        for (int r = 0; r < 16; ++r) {
            int row = (r&3) + 8*(r>>2) + 4*g;
            ob[row*256 + c0]      = __float2bfloat16(acc0[r]);
            ob[(32+row)*256 + c0] = __float2bfloat16(acc1[r]);
        }
        __syncthreads();
        __hip_bfloat16* dst = bufs[tile];
        #pragma unroll
        for (int i = 0; i < 4; ++i) {
            int idx = i*512 + t;               // 64 rows x 32 chunks of 8 bf16
            int row = idx >> 5, ch = idx & 31;
            *(float4*)&dst[(size_t)(base+row)*256 + ch*8] =
                *(const float4*)&ob[row*256 + ch*8];
        }
        __syncthreads();
    }
}

// ---------------- fused edge kernel (512 thr): layer1 -> MFMA layer2 -> MFMA layer3 -> agg ----------------
#define ENPB 8     // nodes per block
#define EEPB 56    // edges per block
#define ARS  264   // activation row stride in bf16 (528 B)
#define MRS  132   // msgbuf row stride in f32 (528 B)

__global__ __launch_bounds__(512, 8)
void edge_kernel(const float* __restrict__ x, const float* __restrict__ u0,
                 const float* __restrict__ msg_w1, const float* __restrict__ gate_w1,
                 const __hip_bfloat16* __restrict__ w2t, const float* __restrict__ msg_b2,
                 const __hip_bfloat16* __restrict__ w3t, const float* __restrict__ msg_b3,
                 const float* __restrict__ gate_w2, const float* __restrict__ gate_b2,
                 const __hip_bfloat16* __restrict__ PAm, const __hip_bfloat16* __restrict__ PBm,
                 const __hip_bfloat16* __restrict__ PAg, const __hip_bfloat16* __restrict__ PBg,
                 const float* __restrict__ TM, const float* __restrict__ TG,
                 __hip_bfloat16* __restrict__ AGG)
{
    __shared__ __align__(16) __hip_bfloat16 act[64*ARS];   // a1 -> a2 -> msgbuf(f32)
    __shared__ __align__(16) float s_rel[EEPB], s_du[EEPB], s_ad[EEPB];
    __shared__ float s_gp[8][28];
    __shared__ int   s_slotj[14];
    __shared__ float s_gate[EEPB];

    const int t    = threadIdx.x;       // 0..511
    const int lane = t & 63;
    const int wv   = t >> 6;            // 0..7
    const int base = blockIdx.x * ENPB;
    const int b    = base >> 12;
    const int ii0  = base & (NXC-1);

    if (t < 14) {
        int jj = ii0 - 3 + t;
        jj = jj < 0 ? 0 : (jj > NXC-1 ? NXC-1 : jj);
        s_slotj[t] = b*NXC + jj;
    }
    if (t < EEPB) {
        int nd = t / 7, s = t - nd*7;
        int i  = base + nd;
        int jj = ii0 + nd + s - 3;
        jj = jj < 0 ? 0 : (jj > NXC-1 ? NXC-1 : jj);
        int j = b*NXC + jj;
        float rel = x[j] - x[i];
        float du  = u0[i] - u0[j];
        s_rel[t] = rel; s_du[t] = du; s_ad[t] = fabsf(du);
    }
    __syncthreads();

    // ---- phase 1: decomposed layer-1 over 28 edges per thread (col = t&255, half = t>>8) ----
    {
        const int col  = t & 255;
        const int half = t >> 8;     // 0/1 ; equals wv>>2
        float wr  = msg_w1 [256*256+col], wd  = msg_w1 [273*256+col], wa  = msg_w1 [274*256+col];
        float gwr = gate_w1[256*256+col], gwd = gate_w1[273*256+col], gwa = gate_w1[274*256+col];
        float tm = TM[b*256+col], tg = TG[b*256+col];
        float g2 = gate_w2[col];
        const f32x2 wr2  = {wr, wr},  wd2  = {wd, wd},  wa2  = {wa, wa};
        const f32x2 gwr2 = {gwr,gwr}, gwd2 = {gwd,gwd}, gwa2 = {gwa,gwa};
        const f32x2 g22  = {g2, g2};
        float bm[10], bg[10], pam[4], pag[4], sacc[7];
        #pragma unroll
        for (int q = 0; q < 10; ++q) {
            size_t o = (size_t)s_slotj[half*4 + q]*256 + col;
            bm[q] = __bfloat162float(PBm[o]) + tm;
            bg[q] = __bfloat162float(PBg[o]) + tg;
        }
        #pragma unroll
        for (int ndl = 0; ndl < 4; ++ndl) {
            size_t o = (size_t)(base + half*4 + ndl)*256 + col;
            pam[ndl] = __bfloat162float(PAm[o]);
            pag[ndl] = __bfloat162float(PAg[o]);
        }
        const bool p1 = (lane & 1), p2 = ((lane & 2) != 0);
        #pragma unroll
        for (int mq = 0; mq < 7; ++mq) {
            float gq[4];
            #pragma unroll
            for (int pp = 0; pp < 2; ++pp) {
                const int el0 = mq*4 + pp*2, el1 = el0 + 1;
                const int e0 = half*28 + el0, e1 = e0 + 1;
                const int ndl0 = el0/7, q0 = ndl0 + (el0 - ndl0*7);
                const int ndl1 = el1/7, q1 = ndl1 + (el1 - ndl1*7);
                f32x2 rel = *(const f32x2*)&s_rel[e0];
                f32x2 du  = *(const f32x2*)&s_du[e0];
                f32x2 ad  = *(const f32x2*)&s_ad[e0];
                f32x2 pm; pm[0] = pam[ndl0] + bm[q0]; pm[1] = pam[ndl1] + bm[q1];
                pm = __builtin_elementwise_fma(rel, wr2, pm);
                pm = __builtin_elementwise_fma(du,  wd2, pm);
                pm = __builtin_elementwise_fma(ad,  wa2, pm);
                f32x2 gm = gelu2(pm);
                act[e0*ARS + col] = __float2bfloat16(gm[0]);
                act[e1*ARS + col] = __float2bfloat16(gm[1]);
                f32x2 pg; pg[0] = pag[ndl0] + bg[q0]; pg[1] = pag[ndl1] + bg[q1];
                pg = __builtin_elementwise_fma(rel, gwr2, pg);
                pg = __builtin_elementwise_fma(du,  gwd2, pg);
                pg = __builtin_elementwise_fma(ad,  gwa2, pg);
                f32x2 gg = gelu2(pg) * g22;
                gq[pp*2] = gg[0]; gq[pp*2+1] = gg[1];
            }
            float xx = p1 ? gq[1] : gq[0], yy = p1 ? gq[0] : gq[1];
            xx += dpp_xor1(yy);
            float zz = p1 ? gq[3] : gq[2], ww = p1 ? gq[2] : gq[3];
            zz += dpp_xor1(ww);
            float uu = p2 ? zz : xx, vv = p2 ? xx : zz;
            uu += dpp_xor2(vv);
            sacc[mq] = uu;
        }
        #pragma unroll
        for (int m = 0; m < 7; ++m) {
            float v = sacc[m];
            v += __shfl_xor(v, 4);
            v += __shfl_xor(v, 8);
            v += __shfl_xor(v, 16);
            v += __shfl_xor(v, 32);
            if (lane < 4) s_gp[wv][m*4 + lane] = v;
        }
    }
    __syncthreads();
    if (t < EEPB) {
        int hf = t / 28, el = t - hf*28;
        float v = s_gp[hf*4+0][el] + s_gp[hf*4+1][el] + s_gp[hf*4+2][el] + s_gp[hf*4+3][el]
                + gate_b2[0];
        s_gate[t] = sigmoid_f(v);
    }

    // ---- layer 2: a2 = gelu(a1 @ w2 + b2); wave wv -> cols wv*32+cl, 2 M-tiles ----
    const int cl = lane & 31;
    const int g  = lane >> 5;
    f32x16 acc0 = zero16(), acc1 = zero16();
    {
        const __hip_bfloat16* w2p = w2t + (size_t)(wv*32 + cl)*256 + g*8;
        const __hip_bfloat16* a1a = act + (size_t)(cl)*ARS + g*8;
        const __hip_bfloat16* a1b = act + (size_t)(32+cl)*ARS + g*8;
        #pragma unroll
        for (int kt = 0; kt < 16; ++kt) {
            bf16x8 bf = *(const bf16x8*)(w2p + kt*16);
            acc0 = MFMA32(*(const bf16x8*)(a1a + kt*16), bf, acc0);
            acc1 = MFMA32(*(const bf16x8*)(a1b + kt*16), bf, acc1);
        }
    }
    __syncthreads();   // a1 reads done; s_gate visible
    {
        const int c0 = wv*32 + cl;
        float b20 = msg_b2[c0];
        #pragma unroll
        for (int r = 0; r < 16; r += 2) {
            int row0 = (r&3) + 8*(r>>2) + 4*g;
            f32x2 v0 = {acc0[r] + b20, acc0[r+1] + b20};
            f32x2 g0 = gelu2(v0);
            act[row0*ARS + c0]     = __float2bfloat16(g0[0]);
            act[(row0+1)*ARS + c0] = __float2bfloat16(g0[1]);
            if (r < 12) {   // rows 32+row0 >= 56 are pad: skip
                int row1 = 32 + row0;
                f32x2 v1 = {acc1[r] + b20, acc1[r+1] + b20};
                f32x2 g1 = gelu2(v1);
                act[row1*ARS + c0]     = __float2bfloat16(g1[0]);
                act[(row1+1)*ARS + c0] = __float2bfloat16(g1[1]);
            }
        }
    }
    __syncthreads();   // a2 complete

    // ---- layer 3: msg = (a2 @ w3 + b3) * gate; wave -> (mt = wv>>2, nt = wv&3) ----
    f32x16 m0 = zero16();
    const int mt = wv >> 2, nt = wv & 3;
    {
        const __hip_bfloat16* w3p = w3t + (size_t)(nt*32 + cl)*256 + g*8;
        const __hip_bfloat16* a2p = act + (size_t)(mt*32 + cl)*ARS + g*8;
        #pragma unroll
        for (int kt = 0; kt < 16; ++kt)
            m0 = MFMA32(*(const bf16x8*)(a2p + kt*16), *(const bf16x8*)(w3p + kt*16), m0);
    }
    __syncthreads();   // a2 reads done -> overwrite act with msgbuf
    float* msgbuf = (float*)act;   // [56][MRS] f32
    {
        const int c = nt*32 + cl;
        float b3v = msg_b3[c];
        #pragma unroll
        for (int r = 0; r < 16; r += 2) {
            int row0 = mt*32 + (r&3) + 8*(r>>2) + 4*g;
            if (row0 + 1 < EEPB) {
                f32x2 mm = {m0[r] + b3v, m0[r+1] + b3v};
                f32x2 gt = {s_gate[row0], s_gate[row0+1]};
                mm *= gt;
                msgbuf[row0*MRS + c]     = mm[0];
                msgbuf[(row0+1)*MRS + c] = mm[1];
            }
        }
    }
    __syncthreads();

    // ---- aggregate the 7 edges of each node (one node per wave) ----
    {
        const int c2 = (t & 63) * 2;
        const int nd = wv;
        f32x2 s = {0.f, 0.f};
        #pragma unroll
        for (int q2 = 0; q2 < 7; ++q2)
            s += *(const f32x2*)&msgbuf[(nd*7+q2)*MRS + c2];
        ushort2 u;
        u.x = (unsigned short)f2bs(s[0]);
        u.y = (unsigned short)f2bs(s[1]);
        *(ushort2*)&AGG[(size_t)(base+nd)*128 + c2] = u;
    }
}

// ---------------- update kernel (MFMA, 512 thr, M=64) ----------------
#define UM 64

__global__ __launch_bounds__(512, 6)
void update_kernel(const __hip_bfloat16* __restrict__ w1ut, const __hip_bfloat16* __restrict__ w2ut,
                   const __hip_bfloat16* __restrict__ w3ut, const __hip_bfloat16* __restrict__ wwt,
                   const float* __restrict__ upd_b2, const float* __restrict__ upd_b3,
                   const float* __restrict__ W_b,
                   const float* __restrict__ h, const __hip_bfloat16* __restrict__ AGG,
                   const float* __restrict__ TU,
                   float* __restrict__ out)
{
    __shared__ __align__(16) __hip_bfloat16 ub[UM*ARS];   // [h|agg] -> u1 -> u2, in place
    const int t = threadIdx.x;          // 0..511
    const int lane = t & 63, wv = t >> 6;
    const int cl = lane & 31, g = lane >> 5;
    const int base = blockIdx.x * UM;
    const int b = base >> 12;
    const int mt = wv >> 2, nt = wv & 3;

    #pragma unroll
    for (int i = 0; i < 4; ++i) {          // stage h tile (64 x 128 f32 -> bf16)
        int f = (i*512 + t)*4;
        int row = f >> 7, col = f & 127;
        float4 hv = *(const float4*)&h[(size_t)base*128 + f];
        s16x4 pk; pk[0]=f2bs(hv.x); pk[1]=f2bs(hv.y); pk[2]=f2bs(hv.z); pk[3]=f2bs(hv.w);
        *(s16x4*)&ub[row*ARS + col] = pk;
    }
    #pragma unroll
    for (int i = 0; i < 2; ++i) {          // stage AGG tile (64 x 128 bf16, direct copy)
        int idx = i*512 + t;               // 64 rows x 16 chunks of 8 bf16
        int row = idx >> 4, ch = idx & 15;
        *(float4*)&ub[row*ARS + 128 + ch*8] =
            *(const float4*)&AGG[(size_t)(base+row)*128 + ch*8];
    }
    __syncthreads();

    // ---- u1 = gelu([h|agg] @ upd_w1 + TU) K=256, N=256; + HL tile (mt,nt) in regs ----
    f32x16 u0a = zero16(), u1a = zero16(), hl = zero16();
    {
        const __hip_bfloat16* a0  = ub + (size_t)(cl)*ARS + g*8;
        const __hip_bfloat16* a1p = ub + (size_t)(32+cl)*ARS + g*8;
        const __hip_bfloat16* ahl = ub + (size_t)(mt*32+cl)*ARS + g*8;
        const __hip_bfloat16* b0 = w1ut + (size_t)(wv*32 + cl)*256 + g*8;
        const __hip_bfloat16* bw = wwt + (size_t)(nt*32 + cl)*128 + g*8;
        #pragma unroll
        for (int kt = 0; kt < 16; ++kt) {
            bf16x8 bf = *(const bf16x8*)(b0 + kt*16);
            u0a = MFMA32(*(const bf16x8*)(a0  + kt*16), bf, u0a);
            u1a = MFMA32(*(const bf16x8*)(a1p + kt*16), bf, u1a);
            if (kt < 8)
                hl = MFMA32(*(const bf16x8*)(ahl + kt*16), *(const bf16x8*)(bw + kt*16), hl);
        }
    }
    __syncthreads();   // staging reads done
    {
        const int c0 = wv*32 + cl;
        float tu0 = TU[b*256 + c0];
        #pragma unroll
        for (int r = 0; r < 16; r += 2) {
            int row = (r&3) + 8*(r>>2) + 4*g;
            f32x2 v0 = {u0a[r] + tu0, u0a[r+1] + tu0};
            f32x2 g0 = gelu2(v0);
            ub[row*ARS + c0]     = __float2bfloat16(g0[0]);
            ub[(row+1)*ARS + c0] = __float2bfloat16(g0[1]);
            f32x2 v1 = {u1a[r] + tu0, u1a[r+1] + tu0};
            f32x2 g1 = gelu2(v1);
            ub[(32+row)*ARS + c0]   = __float2bfloat16(g1[0]);
            ub[(32+row+1)*ARS + c0] = __float2bfloat16(g1[1]);
        }
    }
    __syncthreads();

    // ---- u2 = gelu(u1 @ w2u + b2)  K=256, N=256 ----
    f32x16 v0a = zero16(), v1a = zero16();
    {
        const __hip_bfloat16* a0  = ub + (size_t)(cl)*ARS + g*8;
        const __hip_bfloat16* a1p = ub + (size_t)(32+cl)*ARS + g*8;
        const __hip_bfloat16* b0 = w2ut + (size_t)(wv*32 + cl)*256 + g*8;
        #pragma unroll
        for (int kt = 0; kt < 16; ++kt) {
            bf16x8 bf = *(const bf16x8*)(b0 + kt*16);
            v0a = MFMA32(*(const bf16x8*)(a0  + kt*16), bf, v0a);
            v1a = MFMA32(*(const bf16x8*)(a1p + kt*16), bf, v1a);
        }
    }
    __syncthreads();   // u1 reads done
    {
        const int c0 = wv*32 + cl;
        float b20 = upd_b2[c0];
        #pragma unroll
        for (int r = 0; r < 16; r += 2) {
            int row = (r&3) + 8*(r>>2) + 4*g;
            f32x2 v0 = {v0a[r] + b20, v0a[r+1] + b20};
            f32x2 g0 = gelu2(v0);
            ub[row*ARS + c0]     = __float2bfloat16(g0[0]);
            ub[(row+1)*ARS + c0] = __float2bfloat16(g0[1]);
            f32x2 v1 = {v1a[r] + b20, v1a[r+1] + b20};
            f32x2 g1 = gelu2(v1);
            ub[(32+row)*ARS + c0]   = __float2bfloat16(g1[0]);
            ub[(32+row+1)*ARS + c0] = __float2bfloat16(g1[1]);
        }
    }
    __syncthreads();

    // ---- out = gelu(u2 @ w3u + b3 + HL + W_b); wave -> tile (mt, nt) ----
    f32x16 w0a = zero16();
    {
        const __hip_bfloat16* wp = w3ut + (size_t)(nt*32 + cl)*256 + g*8;
        const __hip_bfloat16* a0 = ub + (size_t)(mt*32 + cl)*ARS + g*8;
        #pragma unroll
        for (int kt = 0; kt < 16; ++kt)
            w0a = MFMA32(*(const bf16x8*)(a0 + kt*16), *(const bf16x8*)(wp + kt*16), w0a);
    }
    {
        const int c = nt*32 + cl;
        float b3v = upd_b3[c] + W_b[c];
        #pragma unroll
        for (int r = 0; r < 16; r += 2) {
            int row = mt*32 + (r&3) + 8*(r>>2) + 4*g;
            f32x2 vv = {w0a[r] + b3v + hl[r], w0a[r+1] + b3v + hl[r+1]};
            f32x2 gg = gelu2(vv);
            out[(size_t)(base+row)*128 + c]   = gg[0];
            out[(size_t)(base+row+1)*128 + c] = gg[1];
        }
    }
}

// ---------------- launch ----------------
extern "C" void kernel_launch(void* const* d_in, const int* in_sizes, int n_in,
                              void* d_out, int out_size, void* d_ws, size_t ws_size,
                              hipStream_t stream)
{
    const float* h      = (const float*)d_in[0];
    const float* x      = (const float*)d_in[1];
    const float* tau    = (const float*)d_in[2];
    const float* u0     = (const float*)d_in[3];
    const float* msg_w1 = (const float*)d_in[4];
    const float* msg_b1 = (const float*)d_in[5];
    const float* msg_w2 = (const float*)d_in[6];
    const float* msg_b2 = (const float*)d_in[7];
    const float* msg_w3 = (const float*)d_in[8];
    const float* msg_b3 = (const float*)d_in[9];
    const float* gate_w1= (const float*)d_in[10];
    const float* gate_b1= (const float*)d_in[11];
    const float* gate_w2= (const float*)d_in[12];
    const float* gate_b2= (const float*)d_in[13];
    const float* upd_w1 = (const float*)d_in[14];
    const float* upd_b1 = (const float*)d_in[15];
    const float* upd_w2 = (const float*)d_in[16];
    const float* upd_b2 = (const float*)d_in[17];
    const float* upd_w3 = (const float*)d_in[18];
    const float* upd_b3 = (const float*)d_in[19];
    const float* W_w    = (const float*)d_in[20];
    const float* W_b    = (const float*)d_in[21];
    float* out = (float*)d_out;

    char* ws = (char*)d_ws;
    size_t off = 0;
    auto alloc = [&](size_t bytes) -> void* {
        void* p = ws + off;
        off += (bytes + 255) & ~(size_t)255;
        return p;
    };
    __hip_bfloat16* PAm = (__hip_bfloat16*)alloc((size_t)NNODES*256*2);
    __hip_bfloat16* PBm = (__hip_bfloat16*)alloc((size_t)NNODES*256*2);
    __hip_bfloat16* PAg = (__hip_bfloat16*)alloc((size_t)NNODES*256*2);
    __hip_bfloat16* PBg = (__hip_bfloat16*)alloc((size_t)NNODES*256*2);
    __hip_bfloat16* AGG = (__hip_bfloat16*)alloc((size_t)NNODES*128*2);
    float* TM  = (float*)alloc(8*256*4);
    float* TG  = (float*)alloc(8*256*4);
    float* TU  = (float*)alloc(8*256*4);
    __hip_bfloat16* w2t   = (__hip_bfloat16*)alloc((size_t)256*256*2);
    __hip_bfloat16* w3t   = (__hip_bfloat16*)alloc((size_t)128*256*2);
    __hip_bfloat16* wall_t= (__hip_bfloat16*)alloc((size_t)1024*128*2);
    __hip_bfloat16* w1ut  = (__hip_bfloat16*)alloc((size_t)256*256*2);
    __hip_bfloat16* w2ut  = (__hip_bfloat16*)alloc((size_t)256*256*2);
    __hip_bfloat16* w3ut  = (__hip_bfloat16*)alloc((size_t)128*256*2);
    __hip_bfloat16* wwt   = (__hip_bfloat16*)alloc((size_t)128*128*2);
    (void)ws_size; (void)in_sizes; (void)n_in; (void)out_size;

    wconv_kernel<<<1608, 256, 0, stream>>>(msg_w2, msg_w3, msg_w1, gate_w1,
                                           upd_w1, upd_w2, upd_w3, W_w,
                                           tau, msg_b1, gate_b1, upd_b1,
                                           w2t, w3t, wall_t, w1ut, w2ut, w3ut, wwt,
                                           TM, TG, TU);
    precompute_kernel<<<NNODES/64, 512, 0, stream>>>(h, wall_t,
                                                     PAm, PBm, PAg, PBg);
    edge_kernel<<<NNODES/ENPB, 512, 0, stream>>>(x, u0, msg_w1, gate_w1,
                                                 w2t, msg_b2, w3t, msg_b3,
                                                 gate_w2, gate_b2,
                                                 PAm, PBm, PAg, PBg, TM, TG, AGG);
    update_kernel<<<NNODES/UM, 512, 0, stream>>>(w1ut, w2ut, w3ut, wwt,
                                                 upd_b2, upd_b3, W_b,
                                                 h, AGG, TU, out);
}

// Round 9
// 272.699 us; speedup vs baseline: 1.0163x; 1.0163x over previous
//
#include <hip/hip_runtime.h>
#include <hip/hip_bf16.h>
#include <math.h>

#define NXC 4096
#define NNODES 32768       // B*NX = 8*4096

typedef __attribute__((ext_vector_type(8))) short bf16x8;
typedef __attribute__((ext_vector_type(4))) short s16x4;
typedef __attribute__((ext_vector_type(16))) float f32x16;
typedef __attribute__((ext_vector_type(2))) float f32x2;

#define MFMA32(a,b,c) __builtin_amdgcn_mfma_f32_32x32x16_bf16((a),(b),(c),0,0,0)

// ---- transcendental-free GELU (quartic erf fit, |err| ~5e-3, under bf16 grid) ----
#define GC4  3.359256e-5f
#define GC3 -0.000850511f
#define GC2  0.00941855f
#define GC1 -0.06622291f
#define GC0  0.3989423f

__device__ __forceinline__ float gelu_f(float x) {
    float xc = fminf(fmaxf(x, -3.0f), 3.0f);
    float s = xc * xc;
    float q = fmaf(s, GC4, GC3);
    q = fmaf(s, q, GC2);
    q = fmaf(s, q, GC1);
    q = fmaf(s, q, GC0);
    return x * fmaf(xc, q, 0.5f);
}
__device__ __forceinline__ f32x2 gelu2(f32x2 x) {
    const f32x2 lo = {-3.0f, -3.0f}, hi = {3.0f, 3.0f};
    const f32x2 c4 = {GC4, GC4}, c3 = {GC3, GC3}, c2 = {GC2, GC2};
    const f32x2 c1 = {GC1, GC1}, c0 = {GC0, GC0}, half = {0.5f, 0.5f};
    f32x2 xc = __builtin_elementwise_min(__builtin_elementwise_max(x, lo), hi);
    f32x2 s = xc * xc;
    f32x2 q = __builtin_elementwise_fma(s, c4, c3);
    q = __builtin_elementwise_fma(s, q, c2);
    q = __builtin_elementwise_fma(s, q, c1);
    q = __builtin_elementwise_fma(s, q, c0);
    return x * __builtin_elementwise_fma(xc, q, half);
}
__device__ __forceinline__ float sigmoid_f(float v) {
    float e = __builtin_amdgcn_exp2f(-1.4426950409f * v);
    return __builtin_amdgcn_rcpf(1.0f + e);
}
__device__ __forceinline__ short f2bs(float x) {
    __hip_bfloat16 b = __float2bfloat16(x);
    union { __hip_bfloat16 h; short s; } u; u.h = b; return u.s;
}
__device__ __forceinline__ f32x16 zero16() {
    f32x16 v;
    #pragma unroll
    for (int i = 0; i < 16; ++i) v[i] = 0.f;
    return v;
}
__device__ __forceinline__ float dpp_xor1(float x) {
    return __int_as_float(__builtin_amdgcn_update_dpp(0, __float_as_int(x), 0xB1, 0xF, 0xF, true));
}
__device__ __forceinline__ float dpp_xor2(float x) {
    return __int_as_float(__builtin_amdgcn_update_dpp(0, __float_as_int(x), 0x4E, 0xF, 0xF, true));
}

// ---------------- weight prep + tau terms (fused) ----------------
__global__ void wconv_kernel(const float* __restrict__ msg_w2, const float* __restrict__ msg_w3,
                             const float* __restrict__ msg_w1, const float* __restrict__ gate_w1,
                             const float* __restrict__ upd_w1, const float* __restrict__ upd_w2,
                             const float* __restrict__ upd_w3, const float* __restrict__ W_w,
                             const float* __restrict__ tau,
                             const float* __restrict__ msg_b1, const float* __restrict__ gate_b1,
                             const float* __restrict__ upd_b1,
                             __hip_bfloat16* __restrict__ w2t, __hip_bfloat16* __restrict__ w3t,
                             __hip_bfloat16* __restrict__ wall_t, __hip_bfloat16* __restrict__ w1ut,
                             __hip_bfloat16* __restrict__ w2ut, __hip_bfloat16* __restrict__ w3ut,
                             __hip_bfloat16* __restrict__ wwt,
                             float* __restrict__ TM, float* __restrict__ TG, float* __restrict__ TU)
{
    if (blockIdx.x >= 1600) {   // tau terms for batch b
        const int b = blockIdx.x - 1600;   // 0..7
        const int t = threadIdx.x;
        float tv[16];
        #pragma unroll
        for (int k = 0; k < 16; ++k) tv[k] = tau[b*16 + k];
        float am = msg_b1[t], ag = gate_b1[t], au = upd_b1[t];
        #pragma unroll
        for (int k = 0; k < 16; ++k) {
            am = fmaf(tv[k], msg_w1 [(257+k)*256 + t], am);
            ag = fmaf(tv[k], gate_w1[(257+k)*256 + t], ag);
            au = fmaf(tv[k], upd_w1 [(256+k)*256 + t], au);
        }
        TM[b*256+t] = am; TG[b*256+t] = ag; TU[b*256+t] = au;
        return;
    }
    int i = blockIdx.x * 256 + threadIdx.x;   // 0 .. 409599
    if (i < 65536) { int c=i>>8, k=i&255; w2t[i] = __float2bfloat16(msg_w2[k*256+c]); return; }
    i -= 65536;
    if (i < 32768) { int c=i>>8, k=i&255; w3t[i] = __float2bfloat16(msg_w3[k*128+c]); return; }
    i -= 32768;
    if (i < 131072) {
        int c = i>>7, k = i&127; float v;
        if      (c <  256) v = msg_w1 [k*256 + c];
        else if (c <  512) v = msg_w1 [(128+k)*256 + (c-256)];
        else if (c <  768) v = gate_w1[k*256 + (c-512)];
        else               v = gate_w1[(128+k)*256 + (c-768)];
        wall_t[i] = __float2bfloat16(v); return;
    }
    i -= 131072;
    if (i < 65536) { int c=i>>8, k=i&255; w1ut[i] = __float2bfloat16(upd_w1[k*256+c]); return; }
    i -= 65536;
    if (i < 65536) { int c=i>>8, k=i&255; w2ut[i] = __float2bfloat16(upd_w2[k*256+c]); return; }
    i -= 65536;
    if (i < 32768) { int c=i>>8, k=i&255; w3ut[i] = __float2bfloat16(upd_w3[k*128+c]); return; }
    i -= 32768;
    { int c=i>>7, k=i&127; wwt[i] = __float2bfloat16(W_w[k*128+c]); }
}

// ---------------- per-node precompute (MFMA): [PAm|PBm|PAg|PBg] = h @ wall ----------------
#define PSTR 136   // h-tile LDS row stride (bf16), 272 B

__global__ __launch_bounds__(256, 3)
void precompute_kernel(const float* __restrict__ h, const __hip_bfloat16* __restrict__ wall_t,
                       __hip_bfloat16* __restrict__ PAm, __hip_bfloat16* __restrict__ PBm,
                       __hip_bfloat16* __restrict__ PAg, __hip_bfloat16* __restrict__ PBg)
{
    __shared__ __align__(16) __hip_bfloat16 hs[64*PSTR];   // 17.4 KB, staged once
    __shared__ __align__(16) __hip_bfloat16 ob[64*256];    // 32.8 KB, per-tile C staging
    const int t = threadIdx.x;
    const int lane = t & 63, wv = t >> 6;
    const int cl = lane & 31, g = lane >> 5;
    const int base = blockIdx.x * 64;

    #pragma unroll
    for (int i = 0; i < 8; ++i) {          // stage h tile (64x128 f32 -> bf16)
        int f = (i*256 + t)*4;
        float4 hv = *(const float4*)&h[(size_t)base*128 + f];
        int row = f >> 7, col = f & 127;
        s16x4 pk; pk[0]=f2bs(hv.x); pk[1]=f2bs(hv.y); pk[2]=f2bs(hv.z); pk[3]=f2bs(hv.w);
        *(s16x4*)&hs[row*PSTR + col] = pk;
    }
    __syncthreads();

    __hip_bfloat16* bufs[4] = {PAm, PBm, PAg, PBg};
    const int c0 = wv*64 + cl, c1 = c0 + 32;
    const __hip_bfloat16* a0  = hs + (size_t)(cl)*PSTR + g*8;
    const __hip_bfloat16* a1p = hs + (size_t)(32+cl)*PSTR + g*8;

    for (int tile = 0; tile < 4; ++tile) {
        f32x16 a00 = zero16(), a01 = zero16(), a10 = zero16(), a11 = zero16();
        {
            const __hip_bfloat16* b0 = wall_t + ((size_t)tile*256 + c0)*128 + g*8;
            const __hip_bfloat16* b1 = wall_t + ((size_t)tile*256 + c1)*128 + g*8;
            #pragma unroll
            for (int kt = 0; kt < 8; ++kt) {
                bf16x8 bf0 = *(const bf16x8*)(b0 + kt*16);
                bf16x8 bf1 = *(const bf16x8*)(b1 + kt*16);
                bf16x8 af0 = *(const bf16x8*)(a0 + kt*16);
                bf16x8 af1 = *(const bf16x8*)(a1p + kt*16);
                a00 = MFMA32(af0, bf0, a00);
                a01 = MFMA32(af0, bf1, a01);
                a10 = MFMA32(af1, bf0, a10);
                a11 = MFMA32(af1, bf1, a11);
            }
        }
        #pragma unroll
        for (int r = 0; r < 16; ++r) {
            int row = (r&3) + 8*(r>>2) + 4*g;
            ob[row*256 + c0]      = __float2bfloat16(a00[r]);
            ob[row*256 + c1]      = __float2bfloat16(a01[r]);
            ob[(32+row)*256 + c0] = __float2bfloat16(a10[r]);
            ob[(32+row)*256 + c1] = __float2bfloat16(a11[r]);
        }
        __syncthreads();
        __hip_bfloat16* dst = bufs[tile];
        #pragma unroll
        for (int i = 0; i < 8; ++i) {
            int idx = i*256 + t;               // 64 rows x 32 chunks of 8 bf16
            int row = idx >> 5, ch = idx & 31;
            *(float4*)&dst[(size_t)(base+row)*256 + ch*8] =
                *(const float4*)&ob[row*256 + ch*8];
        }
        __syncthreads();                       // ob reads done before next tile writes
    }
}

// ---------------- fused edge kernel (ENPB=4, 256 thr): high-occupancy tile ----------------
#define ENPB 4     // nodes per block
#define EEPB 28    // edges per block
#define NSLOT 10   // halo nodes per block (ENPB + 6)
#define ARS  264   // activation row stride in bf16 (528 B)
#define MRS  132   // msgbuf row stride in f32 (528 B)

__global__ __launch_bounds__(256, 6)
void edge_kernel(const float* __restrict__ x, const float* __restrict__ u0,
                 const float* __restrict__ msg_w1, const float* __restrict__ gate_w1,
                 const __hip_bfloat16* __restrict__ w2t, const float* __restrict__ msg_b2,
                 const __hip_bfloat16* __restrict__ w3t, const float* __restrict__ msg_b3,
                 const float* __restrict__ gate_w2, const float* __restrict__ gate_b2,
                 const __hip_bfloat16* __restrict__ PAm, const __hip_bfloat16* __restrict__ PBm,
                 const __hip_bfloat16* __restrict__ PAg, const __hip_bfloat16* __restrict__ PBg,
                 const float* __restrict__ TM, const float* __restrict__ TG,
                 __hip_bfloat16* __restrict__ AGG)
{
    __shared__ __align__(16) __hip_bfloat16 act[32*ARS];   // 16.9 KB: a1 -> a2 -> msgbuf(f32)
    __shared__ __align__(16) float s_rel[EEPB], s_du[EEPB], s_ad[EEPB];
    __shared__ float s_gp[4][EEPB];
    __shared__ int   s_slotj[NSLOT];
    __shared__ float s_gate[EEPB];

    const int t    = threadIdx.x;       // 0..255
    const int lane = t & 63;
    const int wv   = t >> 6;            // 0..3
    const int base = blockIdx.x * ENPB;
    const int b    = base >> 12;
    const int ii0  = base & (NXC-1);

    if (t < NSLOT) {
        int jj = ii0 - 3 + t;
        jj = jj < 0 ? 0 : (jj > NXC-1 ? NXC-1 : jj);
        s_slotj[t] = b*NXC + jj;
    }
    if (t < EEPB) {
        int nd = t / 7, s = t - nd*7;
        int i  = base + nd;
        int jj = ii0 + nd + s - 3;
        jj = jj < 0 ? 0 : (jj > NXC-1 ? NXC-1 : jj);
        int j = b*NXC + jj;
        float rel = x[j] - x[i];
        float du  = u0[i] - u0[j];
        s_rel[t] = rel; s_du[t] = du; s_ad[t] = fabsf(du);
    }
    if (t < 128) {  // zero pad rows 28..31 (data region: 512 B each)
        int row = 28 + (t >> 5);
        float4 z = {0.f, 0.f, 0.f, 0.f};
        *(float4*)((char*)act + (size_t)row*528 + (size_t)(t & 31)*16) = z;
    }
    __syncthreads();

    // ---- phase 1: decomposed layer-1; col = t over all 28 edges ----
    {
        float wr  = msg_w1 [256*256+t], wd  = msg_w1 [273*256+t], wa  = msg_w1 [274*256+t];
        float gwr = gate_w1[256*256+t], gwd = gate_w1[273*256+t], gwa = gate_w1[274*256+t];
        float tm = TM[b*256+t], tg = TG[b*256+t];
        float g2 = gate_w2[t];
        const f32x2 wr2  = {wr, wr},  wd2  = {wd, wd},  wa2  = {wa, wa};
        const f32x2 gwr2 = {gwr,gwr}, gwd2 = {gwd,gwd}, gwa2 = {gwa,gwa};
        const f32x2 g22  = {g2, g2};
        float bm[NSLOT], bg[NSLOT], pam[ENPB], pag[ENPB], sacc[7];
        #pragma unroll
        for (int q = 0; q < NSLOT; ++q) {
            size_t o = (size_t)s_slotj[q]*256 + t;
            bm[q] = __bfloat162float(PBm[o]) + tm;
            bg[q] = __bfloat162float(PBg[o]) + tg;
        }
        #pragma unroll
        for (int ndl = 0; ndl < ENPB; ++ndl) {
            size_t o = (size_t)(base + ndl)*256 + t;
            pam[ndl] = __bfloat162float(PAm[o]);
            pag[ndl] = __bfloat162float(PAg[o]);
        }
        const bool p1 = (lane & 1), p2 = ((lane & 2) != 0);
        #pragma unroll
        for (int mq = 0; mq < 7; ++mq) {
            float gq[4];
            #pragma unroll
            for (int pp = 0; pp < 2; ++pp) {
                const int e0 = mq*4 + pp*2, e1 = e0 + 1;
                const int nd0 = e0/7, q0 = nd0 + (e0 - nd0*7);
                const int nd1 = e1/7, q1 = nd1 + (e1 - nd1*7);
                f32x2 rel = *(const f32x2*)&s_rel[e0];
                f32x2 du  = *(const f32x2*)&s_du[e0];
                f32x2 ad  = *(const f32x2*)&s_ad[e0];
                f32x2 pm; pm[0] = pam[nd0] + bm[q0]; pm[1] = pam[nd1] + bm[q1];
                pm = __builtin_elementwise_fma(rel, wr2, pm);
                pm = __builtin_elementwise_fma(du,  wd2, pm);
                pm = __builtin_elementwise_fma(ad,  wa2, pm);
                f32x2 gm = gelu2(pm);
                act[e0*ARS + t] = __float2bfloat16(gm[0]);
                act[e1*ARS + t] = __float2bfloat16(gm[1]);
                f32x2 pg; pg[0] = pag[nd0] + bg[q0]; pg[1] = pag[nd1] + bg[q1];
                pg = __builtin_elementwise_fma(rel, gwr2, pg);
                pg = __builtin_elementwise_fma(du,  gwd2, pg);
                pg = __builtin_elementwise_fma(ad,  gwa2, pg);
                f32x2 gg = gelu2(pg) * g22;
                gq[pp*2] = gg[0]; gq[pp*2+1] = gg[1];
            }
            float xx = p1 ? gq[1] : gq[0], yy = p1 ? gq[0] : gq[1];
            xx += dpp_xor1(yy);
            float zz = p1 ? gq[3] : gq[2], ww = p1 ? gq[2] : gq[3];
            zz += dpp_xor1(ww);
            float uu = p2 ? zz : xx, vv = p2 ? xx : zz;
            uu += dpp_xor2(vv);
            sacc[mq] = uu;
        }
        #pragma unroll
        for (int m = 0; m < 7; ++m) {
            float v = sacc[m];
            v += __shfl_xor(v, 4);
            v += __shfl_xor(v, 8);
            v += __shfl_xor(v, 16);
            v += __shfl_xor(v, 32);
            if (lane < 4) s_gp[wv][m*4 + lane] = v;
        }
    }
    __syncthreads();
    if (t < EEPB)
        s_gate[t] = sigmoid_f(s_gp[0][t] + s_gp[1][t] + s_gp[2][t] + s_gp[3][t] + gate_b2[0]);

    // ---- layer 2: a2 = gelu(a1 @ w2 + b2); wave wv -> cols wv*64+cl, +32; 1 M-tile ----
    const int cl = lane & 31;
    const int g  = lane >> 5;
    f32x16 acc0 = zero16(), acc1 = zero16();
    {
        const __hip_bfloat16* w2a = w2t + (size_t)(wv*64 + cl)*256 + g*8;
        const __hip_bfloat16* w2b = w2t + (size_t)(wv*64 + 32 + cl)*256 + g*8;
        const __hip_bfloat16* a1a = act + (size_t)(cl)*ARS + g*8;
        #pragma unroll
        for (int kt = 0; kt < 16; ++kt) {
            bf16x8 af = *(const bf16x8*)(a1a + kt*16);
            acc0 = MFMA32(af, *(const bf16x8*)(w2a + kt*16), acc0);
            acc1 = MFMA32(af, *(const bf16x8*)(w2b + kt*16), acc1);
        }
    }
    __syncthreads();   // a1 reads done; s_gate visible
    {
        const int c0 = wv*64 + cl, c1 = c0 + 32;
        float b20 = msg_b2[c0], b21 = msg_b2[c1];
        #pragma unroll
        for (int r = 0; r < 16; r += 2) {
            int row0 = (r&3) + 8*(r>>2) + 4*g;   // even, 0..30
            f32x2 v0 = {acc0[r] + b20, acc0[r+1] + b20};
            f32x2 g0 = gelu2(v0);
            act[row0*ARS + c0]     = __float2bfloat16(g0[0]);
            act[(row0+1)*ARS + c0] = __float2bfloat16(g0[1]);
            f32x2 v1 = {acc1[r] + b21, acc1[r+1] + b21};
            f32x2 g1 = gelu2(v1);
            act[row0*ARS + c1]     = __float2bfloat16(g1[0]);
            act[(row0+1)*ARS + c1] = __float2bfloat16(g1[1]);
        }
    }
    __syncthreads();   // a2 complete

    // ---- layer 3: msg = (a2 @ w3 + b3) * gate; wave wv -> N-tile wv ----
    f32x16 m0 = zero16();
    {
        const __hip_bfloat16* w3p = w3t + (size_t)(wv*32 + cl)*256 + g*8;
        const __hip_bfloat16* a2p = act + (size_t)(cl)*ARS + g*8;
        #pragma unroll
        for (int kt = 0; kt < 16; ++kt)
            m0 = MFMA32(*(const bf16x8*)(a2p + kt*16), *(const bf16x8*)(w3p + kt*16), m0);
    }
    __syncthreads();   // a2 reads done -> overwrite act with msgbuf
    float* msgbuf = (float*)act;   // [28][MRS] f32
    {
        const int c = wv*32 + cl;
        float b3v = msg_b3[c];
        #pragma unroll
        for (int r = 0; r < 16; r += 2) {
            int row0 = (r&3) + 8*(r>>2) + 4*g;   // even
            if (row0 + 1 < EEPB) {
                f32x2 mm = {m0[r] + b3v, m0[r+1] + b3v};
                f32x2 gt = {s_gate[row0], s_gate[row0+1]};
                mm *= gt;
                msgbuf[row0*MRS + c]     = mm[0];
                msgbuf[(row0+1)*MRS + c] = mm[1];
            }
        }
    }
    __syncthreads();

    // ---- aggregate the 7 edges of each node (one node per wave) ----
    {
        const int c2 = (t & 63) * 2;
        const int nd = wv;
        f32x2 s = {0.f, 0.f};
        #pragma unroll
        for (int q2 = 0; q2 < 7; ++q2)
            s += *(const f32x2*)&msgbuf[(nd*7+q2)*MRS + c2];
        ushort2 u;
        u.x = (unsigned short)f2bs(s[0]);
        u.y = (unsigned short)f2bs(s[1]);
        *(ushort2*)&AGG[(size_t)(base+nd)*128 + c2] = u;
    }
}

// ---------------- update kernel (MFMA, M=32): u1 (incl h-part), u2, u3 + local + final gelu ----------------
#define UM 32

__global__ __launch_bounds__(256, 4)
void update_kernel(const __hip_bfloat16* __restrict__ w1ut, const __hip_bfloat16* __restrict__ w2ut,
                   const __hip_bfloat16* __restrict__ w3ut, const __hip_bfloat16* __restrict__ wwt,
                   const float* __restrict__ upd_b2, const float* __restrict__ upd_b3,
                   const float* __restrict__ W_b,
                   const float* __restrict__ h, const __hip_bfloat16* __restrict__ AGG,
                   const float* __restrict__ TU,
                   float* __restrict__ out)
{
    __shared__ __align__(16) __hip_bfloat16 ub[UM*ARS];   // [h|agg] -> u1 -> u2, in place
    const int t = threadIdx.x;
    const int lane = t & 63, wv = t >> 6;
    const int cl = lane & 31, g = lane >> 5;
    const int base = blockIdx.x * UM;
    const int b = base >> 12;

    #pragma unroll
    for (int i = 0; i < 4; ++i) {          // stage h tile (32 x 128 f32 -> bf16)
        int f = (i*256 + t)*4;
        int row = f >> 7, col = f & 127;
        float4 hv = *(const float4*)&h[(size_t)base*128 + f];
        s16x4 pk; pk[0]=f2bs(hv.x); pk[1]=f2bs(hv.y); pk[2]=f2bs(hv.z); pk[3]=f2bs(hv.w);
        *(s16x4*)&ub[row*ARS + col] = pk;
    }
    #pragma unroll
    for (int i = 0; i < 2; ++i) {          // stage AGG tile (32 x 128 bf16, direct copy)
        int idx = i*256 + t;               // 32 rows x 16 chunks of 8 bf16
        int row = idx >> 4, ch = idx & 15;
        *(float4*)&ub[row*ARS + 128 + ch*8] =
            *(const float4*)&AGG[(size_t)(base+row)*128 + ch*8];
    }
    __syncthreads();

    // ---- u1 = gelu([h|agg] @ upd_w1[0:256] + TU)  K=256, N=256 ----
    // ---- also HL = h @ W_w (K=128, N=128), kept in registers ----
    f32x16 u0a = zero16(), u1a = zero16(), hl = zero16();
    {
        const __hip_bfloat16* a0 = ub + (size_t)(cl)*ARS + g*8;
        const __hip_bfloat16* b0 = w1ut + (size_t)(wv*64 + cl)*256 + g*8;
        const __hip_bfloat16* b1 = w1ut + (size_t)(wv*64 + 32 + cl)*256 + g*8;
        const __hip_bfloat16* bw = wwt + (size_t)(wv*32 + cl)*128 + g*8;
        #pragma unroll
        for (int kt = 0; kt < 16; ++kt) {
            bf16x8 af = *(const bf16x8*)(a0 + kt*16);
            u0a = MFMA32(af, *(const bf16x8*)(b0 + kt*16), u0a);
            u1a = MFMA32(af, *(const bf16x8*)(b1 + kt*16), u1a);
            if (kt < 8)
                hl = MFMA32(af, *(const bf16x8*)(bw + kt*16), hl);
        }
    }
    __syncthreads();   // staging reads done
    {
        const int c0 = wv*64 + cl, c1 = c0 + 32;
        float tu0 = TU[b*256 + c0], tu1 = TU[b*256 + c1];
        #pragma unroll
        for (int r = 0; r < 16; r += 2) {
            int row = (r&3) + 8*(r>>2) + 4*g;
            f32x2 v0 = {u0a[r] + tu0, u0a[r+1] + tu0};
            f32x2 g0 = gelu2(v0);
            ub[row*ARS + c0]     = __float2bfloat16(g0[0]);
            ub[(row+1)*ARS + c0] = __float2bfloat16(g0[1]);
            f32x2 v1 = {u1a[r] + tu1, u1a[r+1] + tu1};
            f32x2 g1 = gelu2(v1);
            ub[row*ARS + c1]     = __float2bfloat16(g1[0]);
            ub[(row+1)*ARS + c1] = __float2bfloat16(g1[1]);
        }
    }
    __syncthreads();

    // ---- u2 = gelu(u1 @ w2u + b2)  K=256, N=256 ----
    f32x16 v0a = zero16(), v1a = zero16();
    {
        const __hip_bfloat16* a0 = ub + (size_t)(cl)*ARS + g*8;
        const __hip_bfloat16* b0 = w2ut + (size_t)(wv*64 + cl)*256 + g*8;
        const __hip_bfloat16* b1 = w2ut + (size_t)(wv*64 + 32 + cl)*256 + g*8;
        #pragma unroll
        for (int kt = 0; kt < 16; ++kt) {
            bf16x8 af = *(const bf16x8*)(a0 + kt*16);
            v0a = MFMA32(af, *(const bf16x8*)(b0 + kt*16), v0a);
            v1a = MFMA32(af, *(const bf16x8*)(b1 + kt*16), v1a);
        }
    }
    __syncthreads();   // u1 reads done
    {
        const int c0 = wv*64 + cl, c1 = c0 + 32;
        float b20 = upd_b2[c0], b21 = upd_b2[c1];
        #pragma unroll
        for (int r = 0; r < 16; r += 2) {
            int row = (r&3) + 8*(r>>2) + 4*g;
            f32x2 v0 = {v0a[r] + b20, v0a[r+1] + b20};
            f32x2 g0 = gelu2(v0);
            ub[row*ARS + c0]     = __float2bfloat16(g0[0]);
            ub[(row+1)*ARS + c0] = __float2bfloat16(g0[1]);
            f32x2 v1 = {v1a[r] + b21, v1a[r+1] + b21};
            f32x2 g1 = gelu2(v1);
            ub[row*ARS + c1]     = __float2bfloat16(g1[0]);
            ub[(row+1)*ARS + c1] = __float2bfloat16(g1[1]);
        }
    }
    __syncthreads();

    // ---- out = gelu(u2 @ w3u + b3 + HL + W_b)  K=256, N=128 ----
    f32x16 w0a = zero16();
    {
        const __hip_bfloat16* wp = w3ut + (size_t)(wv*32 + cl)*256 + g*8;
        const __hip_bfloat16* a0 = ub + (size_t)(cl)*ARS + g*8;
        #pragma unroll
        for (int kt = 0; kt < 16; ++kt)
            w0a = MFMA32(*(const bf16x8*)(a0 + kt*16), *(const bf16x8*)(wp + kt*16), w0a);
    }
    {
        const int c = wv*32 + cl;
        float b3v = upd_b3[c] + W_b[c];
        #pragma unroll
        for (int r = 0; r < 16; r += 2) {
            int row = (r&3) + 8*(r>>2) + 4*g;
            f32x2 vv = {w0a[r] + b3v + hl[r], w0a[r+1] + b3v + hl[r+1]};
            f32x2 gg = gelu2(vv);
            size_t o0 = (size_t)(base+row)*128 + c;
            size_t o1 = (size_t)(base+row+1)*128 + c;
            out[o0] = gg[0];
            out[o1] = gg[1];
        }
    }
}

// ---------------- launch ----------------
extern "C" void kernel_launch(void* const* d_in, const int* in_sizes, int n_in,
                              void* d_out, int out_size, void* d_ws, size_t ws_size,
                              hipStream_t stream)
{
    const float* h      = (const float*)d_in[0];
    const float* x      = (const float*)d_in[1];
    const float* tau    = (const float*)d_in[2];
    const float* u0     = (const float*)d_in[3];
    const float* msg_w1 = (const float*)d_in[4];
    const float* msg_b1 = (const float*)d_in[5];
    const float* msg_w2 = (const float*)d_in[6];
    const float* msg_b2 = (const float*)d_in[7];
    const float* msg_w3 = (const float*)d_in[8];
    const float* msg_b3 = (const float*)d_in[9];
    const float* gate_w1= (const float*)d_in[10];
    const float* gate_b1= (const float*)d_in[11];
    const float* gate_w2= (const float*)d_in[12];
    const float* gate_b2= (const float*)d_in[13];
    const float* upd_w1 = (const float*)d_in[14];
    const float* upd_b1 = (const float*)d_in[15];
    const float* upd_w2 = (const float*)d_in[16];
    const float* upd_b2 = (const float*)d_in[17];
    const float* upd_w3 = (const float*)d_in[18];
    const float* upd_b3 = (const float*)d_in[19];
    const float* W_w    = (const float*)d_in[20];
    const float* W_b    = (const float*)d_in[21];
    float* out = (float*)d_out;

    char* ws = (char*)d_ws;
    size_t off = 0;
    auto alloc = [&](size_t bytes) -> void* {
        void* p = ws + off;
        off += (bytes + 255) & ~(size_t)255;
        return p;
    };
    __hip_bfloat16* PAm = (__hip_bfloat16*)alloc((size_t)NNODES*256*2);
    __hip_bfloat16* PBm = (__hip_bfloat16*)alloc((size_t)NNODES*256*2);
    __hip_bfloat16* PAg = (__hip_bfloat16*)alloc((size_t)NNODES*256*2);
    __hip_bfloat16* PBg = (__hip_bfloat16*)alloc((size_t)NNODES*256*2);
    __hip_bfloat16* AGG = (__hip_bfloat16*)alloc((size_t)NNODES*128*2);
    float* TM  = (float*)alloc(8*256*4);
    float* TG  = (float*)alloc(8*256*4);
    float* TU  = (float*)alloc(8*256*4);
    __hip_bfloat16* w2t   = (__hip_bfloat16*)alloc((size_t)256*256*2);
    __hip_bfloat16* w3t   = (__hip_bfloat16*)alloc((size_t)128*256*2);
    __hip_bfloat16* wall_t= (__hip_bfloat16*)alloc((size_t)1024*128*2);
    __hip_bfloat16* w1ut  = (__hip_bfloat16*)alloc((size_t)256*256*2);
    __hip_bfloat16* w2ut  = (__hip_bfloat16*)alloc((size_t)256*256*2);
    __hip_bfloat16* w3ut  = (__hip_bfloat16*)alloc((size_t)128*256*2);
    __hip_bfloat16* wwt   = (__hip_bfloat16*)alloc((size_t)128*128*2);
    (void)ws_size; (void)in_sizes; (void)n_in; (void)out_size;

    wconv_kernel<<<1608, 256, 0, stream>>>(msg_w2, msg_w3, msg_w1, gate_w1,
                                           upd_w1, upd_w2, upd_w3, W_w,
                                           tau, msg_b1, gate_b1, upd_b1,
                                           w2t, w3t, wall_t, w1ut, w2ut, w3ut, wwt,
                                           TM, TG, TU);
    precompute_kernel<<<NNODES/64, 256, 0, stream>>>(h, wall_t,
                                                     PAm, PBm, PAg, PBg);
    edge_kernel<<<NNODES/ENPB, 256, 0, stream>>>(x, u0, msg_w1, gate_w1,
                                                 w2t, msg_b2, w3t, msg_b3,
                                                 gate_w2, gate_b2,
                                                 PAm, PBm, PAg, PBg, TM, TG, AGG);
    update_kernel<<<NNODES/UM, 256, 0, stream>>>(w1ut, w2ut, w3ut, wwt,
                                                 upd_b2, upd_b3, W_b,
                                                 h, AGG, TU, out);
}

// Round 10
// 193.695 us; speedup vs baseline: 1.4308x; 1.4079x over previous
//
#include <hip/hip_runtime.h>
#include <hip/hip_bf16.h>
#include <math.h>

#define NXC 4096
#define NNODES 32768       // B*NX = 8*4096

typedef __attribute__((ext_vector_type(8))) short bf16x8;
typedef __attribute__((ext_vector_type(4))) short s16x4;
typedef __attribute__((ext_vector_type(16))) float f32x16;
typedef __attribute__((ext_vector_type(2))) float f32x2;

#define MFMA32(a,b,c) __builtin_amdgcn_mfma_f32_32x32x16_bf16((a),(b),(c),0,0,0)

// ---- transcendental-free GELU (quartic erf fit, |err| ~5e-3, under bf16 grid) ----
#define GC4  3.359256e-5f
#define GC3 -0.000850511f
#define GC2  0.00941855f
#define GC1 -0.06622291f
#define GC0  0.3989423f

__device__ __forceinline__ float gelu_f(float x) {
    float xc = fminf(fmaxf(x, -3.0f), 3.0f);
    float s = xc * xc;
    float q = fmaf(s, GC4, GC3);
    q = fmaf(s, q, GC2);
    q = fmaf(s, q, GC1);
    q = fmaf(s, q, GC0);
    return x * fmaf(xc, q, 0.5f);
}
__device__ __forceinline__ f32x2 gelu2(f32x2 x) {
    const f32x2 lo = {-3.0f, -3.0f}, hi = {3.0f, 3.0f};
    const f32x2 c4 = {GC4, GC4}, c3 = {GC3, GC3}, c2 = {GC2, GC2};
    const f32x2 c1 = {GC1, GC1}, c0 = {GC0, GC0}, half = {0.5f, 0.5f};
    f32x2 xc = __builtin_elementwise_min(__builtin_elementwise_max(x, lo), hi);
    f32x2 s = xc * xc;
    f32x2 q = __builtin_elementwise_fma(s, c4, c3);
    q = __builtin_elementwise_fma(s, q, c2);
    q = __builtin_elementwise_fma(s, q, c1);
    q = __builtin_elementwise_fma(s, q, c0);
    return x * __builtin_elementwise_fma(xc, q, half);
}
__device__ __forceinline__ float sigmoid_f(float v) {
    float e = __builtin_amdgcn_exp2f(-1.4426950409f * v);
    return __builtin_amdgcn_rcpf(1.0f + e);
}
__device__ __forceinline__ short f2bs(float x) {
    __hip_bfloat16 b = __float2bfloat16(x);
    union { __hip_bfloat16 h; short s; } u; u.h = b; return u.s;
}
__device__ __forceinline__ f32x16 zero16() {
    f32x16 v;
    #pragma unroll
    for (int i = 0; i < 16; ++i) v[i] = 0.f;
    return v;
}
__device__ __forceinline__ float dpp_xor1(float x) {
    return __int_as_float(__builtin_amdgcn_update_dpp(0, __float_as_int(x), 0xB1, 0xF, 0xF, true));
}
__device__ __forceinline__ float dpp_xor2(float x) {
    return __int_as_float(__builtin_amdgcn_update_dpp(0, __float_as_int(x), 0x4E, 0xF, 0xF, true));
}

// ---------------- weight prep + tau terms (fused) ----------------
__global__ void wconv_kernel(const float* __restrict__ msg_w2, const float* __restrict__ msg_w3,
                             const float* __restrict__ msg_w1, const float* __restrict__ gate_w1,
                             const float* __restrict__ upd_w1, const float* __restrict__ upd_w2,
                             const float* __restrict__ upd_w3, const float* __restrict__ W_w,
                             const float* __restrict__ tau,
                             const float* __restrict__ msg_b1, const float* __restrict__ gate_b1,
                             const float* __restrict__ upd_b1,
                             __hip_bfloat16* __restrict__ w2t, __hip_bfloat16* __restrict__ w3t,
                             __hip_bfloat16* __restrict__ wall_t, __hip_bfloat16* __restrict__ w1ut,
                             __hip_bfloat16* __restrict__ w2ut, __hip_bfloat16* __restrict__ w3ut,
                             __hip_bfloat16* __restrict__ wwt,
                             float* __restrict__ TM, float* __restrict__ TG, float* __restrict__ TU)
{
    if (blockIdx.x >= 1600) {   // tau terms for batch b
        const int b = blockIdx.x - 1600;   // 0..7
        const int t = threadIdx.x;
        float tv[16];
        #pragma unroll
        for (int k = 0; k < 16; ++k) tv[k] = tau[b*16 + k];
        float am = msg_b1[t], ag = gate_b1[t], au = upd_b1[t];
        #pragma unroll
        for (int k = 0; k < 16; ++k) {
            am = fmaf(tv[k], msg_w1 [(257+k)*256 + t], am);
            ag = fmaf(tv[k], gate_w1[(257+k)*256 + t], ag);
            au = fmaf(tv[k], upd_w1 [(256+k)*256 + t], au);
        }
        TM[b*256+t] = am; TG[b*256+t] = ag; TU[b*256+t] = au;
        return;
    }
    int i = blockIdx.x * 256 + threadIdx.x;   // 0 .. 409599
    if (i < 65536) { int c=i>>8, k=i&255; w2t[i] = __float2bfloat16(msg_w2[k*256+c]); return; }
    i -= 65536;
    if (i < 32768) { int c=i>>8, k=i&255; w3t[i] = __float2bfloat16(msg_w3[k*128+c]); return; }
    i -= 32768;
    if (i < 131072) {
        int c = i>>7, k = i&127; float v;
        if      (c <  256) v = msg_w1 [k*256 + c];
        else if (c <  512) v = msg_w1 [(128+k)*256 + (c-256)];
        else if (c <  768) v = gate_w1[k*256 + (c-512)];
        else               v = gate_w1[(128+k)*256 + (c-768)];
        wall_t[i] = __float2bfloat16(v); return;
    }
    i -= 131072;
    if (i < 65536) { int c=i>>8, k=i&255; w1ut[i] = __float2bfloat16(upd_w1[k*256+c]); return; }
    i -= 65536;
    if (i < 65536) { int c=i>>8, k=i&255; w2ut[i] = __float2bfloat16(upd_w2[k*256+c]); return; }
    i -= 65536;
    if (i < 32768) { int c=i>>8, k=i&255; w3ut[i] = __float2bfloat16(upd_w3[k*128+c]); return; }
    i -= 32768;
    { int c=i>>7, k=i&127; wwt[i] = __float2bfloat16(W_w[k*128+c]); }
}

// ---------------- per-node precompute (MFMA): [PAm|PBm|PAg|PBg] = h @ wall ----------------
#define PSTR 136   // h-tile LDS row stride (bf16), 272 B

__global__ __launch_bounds__(256, 3)
void precompute_kernel(const float* __restrict__ h, const __hip_bfloat16* __restrict__ wall_t,
                       __hip_bfloat16* __restrict__ PAm, __hip_bfloat16* __restrict__ PBm,
                       __hip_bfloat16* __restrict__ PAg, __hip_bfloat16* __restrict__ PBg)
{
    __shared__ __align__(16) __hip_bfloat16 hs[64*PSTR];   // 17.4 KB, staged once
    __shared__ __align__(16) __hip_bfloat16 ob[64*256];    // 32.8 KB, per-tile C staging
    const int t = threadIdx.x;
    const int lane = t & 63, wv = t >> 6;
    const int cl = lane & 31, g = lane >> 5;
    const int base = blockIdx.x * 64;

    #pragma unroll
    for (int i = 0; i < 8; ++i) {          // stage h tile (64x128 f32 -> bf16)
        int f = (i*256 + t)*4;
        float4 hv = *(const float4*)&h[(size_t)base*128 + f];
        int row = f >> 7, col = f & 127;
        s16x4 pk; pk[0]=f2bs(hv.x); pk[1]=f2bs(hv.y); pk[2]=f2bs(hv.z); pk[3]=f2bs(hv.w);
        *(s16x4*)&hs[row*PSTR + col] = pk;
    }
    __syncthreads();

    __hip_bfloat16* bufs[4] = {PAm, PBm, PAg, PBg};
    const int c0 = wv*64 + cl, c1 = c0 + 32;
    const __hip_bfloat16* a0  = hs + (size_t)(cl)*PSTR + g*8;
    const __hip_bfloat16* a1p = hs + (size_t)(32+cl)*PSTR + g*8;

    for (int tile = 0; tile < 4; ++tile) {
        f32x16 a00 = zero16(), a01 = zero16(), a10 = zero16(), a11 = zero16();
        {
            const __hip_bfloat16* b0 = wall_t + ((size_t)tile*256 + c0)*128 + g*8;
            const __hip_bfloat16* b1 = wall_t + ((size_t)tile*256 + c1)*128 + g*8;
            #pragma unroll
            for (int kt = 0; kt < 8; ++kt) {
                bf16x8 bf0 = *(const bf16x8*)(b0 + kt*16);
                bf16x8 bf1 = *(const bf16x8*)(b1 + kt*16);
                bf16x8 af0 = *(const bf16x8*)(a0 + kt*16);
                bf16x8 af1 = *(const bf16x8*)(a1p + kt*16);
                a00 = MFMA32(af0, bf0, a00);
                a01 = MFMA32(af0, bf1, a01);
                a10 = MFMA32(af1, bf0, a10);
                a11 = MFMA32(af1, bf1, a11);
            }
        }
        #pragma unroll
        for (int r = 0; r < 16; ++r) {
            int row = (r&3) + 8*(r>>2) + 4*g;
            ob[row*256 + c0]      = __float2bfloat16(a00[r]);
            ob[row*256 + c1]      = __float2bfloat16(a01[r]);
            ob[(32+row)*256 + c0] = __float2bfloat16(a10[r]);
            ob[(32+row)*256 + c1] = __float2bfloat16(a11[r]);
        }
        __syncthreads();
        __hip_bfloat16* dst = bufs[tile];
        #pragma unroll
        for (int i = 0; i < 8; ++i) {
            int idx = i*256 + t;               // 64 rows x 32 chunks of 8 bf16
            int row = idx >> 5, ch = idx & 31;
            *(float4*)&dst[(size_t)(base+row)*256 + ch*8] =
                *(const float4*)&ob[row*256 + ch*8];
        }
        __syncthreads();                       // ob reads done before next tile writes
    }
}

// ---------------- fused edge kernel (ENPB=8, 256 thr, early-issue loads + XCD swizzle) ----------------
#define ENPB 8     // nodes per block
#define EEPB 56    // edges per block
#define ARS  264   // activation row stride in bf16 (528 B)
#define MRS  132   // msgbuf row stride in f32 (528 B)

__global__ __launch_bounds__(256, 4)
void edge_kernel(const float* __restrict__ x, const float* __restrict__ u0,
                 const float* __restrict__ msg_w1, const float* __restrict__ gate_w1,
                 const __hip_bfloat16* __restrict__ w2t, const float* __restrict__ msg_b2,
                 const __hip_bfloat16* __restrict__ w3t, const float* __restrict__ msg_b3,
                 const float* __restrict__ gate_w2, const float* __restrict__ gate_b2,
                 const __hip_bfloat16* __restrict__ PAm, const __hip_bfloat16* __restrict__ PBm,
                 const __hip_bfloat16* __restrict__ PAg, const __hip_bfloat16* __restrict__ PBg,
                 const float* __restrict__ TM, const float* __restrict__ TG,
                 __hip_bfloat16* __restrict__ AGG)
{
    __shared__ __align__(16) __hip_bfloat16 act[64*ARS];   // a1 -> a2 -> msgbuf(f32)
    __shared__ __align__(16) float s_rel[EEPB], s_du[EEPB], s_ad[EEPB];
    __shared__ float s_gp[4][EEPB];
    __shared__ float s_gate[EEPB];

    const int t    = threadIdx.x;
    const int lane = t & 63;
    const int wv   = t >> 6;
    // XCD-aware swizzle: 4096 blocks = 8 XCDs x 512 contiguous tiles
    const int wg   = ((int)blockIdx.x & 7) * ((int)gridDim.x >> 3) + ((int)blockIdx.x >> 3);
    const int base = wg * ENPB;
    const int b    = base >> 12;
    const int ii0  = base & (NXC-1);

    // ---- EARLY ISSUE: all phase-1 global loads, arithmetic indices, no LDS/barrier dep ----
    float bm[14], bg[14], pam[8], pag[8];
    #pragma unroll
    for (int q = 0; q < 14; ++q) {
        int jj = ii0 - 3 + q;
        jj = jj < 0 ? 0 : (jj > NXC-1 ? NXC-1 : jj);
        size_t o = ((size_t)(b*NXC + jj))*256 + t;
        bm[q] = __bfloat162float(PBm[o]);
        bg[q] = __bfloat162float(PBg[o]);
    }
    #pragma unroll
    for (int nd = 0; nd < 8; ++nd) {
        size_t o = (size_t)(base+nd)*256 + t;
        pam[nd] = __bfloat162float(PAm[o]);
        pag[nd] = __bfloat162float(PAg[o]);
    }
    const float wr  = msg_w1 [256*256+t], wd  = msg_w1 [273*256+t], wa  = msg_w1 [274*256+t];
    const float gwr = gate_w1[256*256+t], gwd = gate_w1[273*256+t], gwa = gate_w1[274*256+t];
    const float tm = TM[b*256+t], tg = TG[b*256+t];
    const float g2 = gate_w2[t];

    if (t < EEPB) {
        int nd = t / 7, s = t - nd*7;
        int i  = base + nd;
        int jj = ii0 + nd + s - 3;
        jj = jj < 0 ? 0 : (jj > NXC-1 ? NXC-1 : jj);
        int j = b*NXC + jj;
        float rel = x[j] - x[i];
        float du  = u0[i] - u0[j];
        s_rel[t] = rel; s_du[t] = du; s_ad[t] = fabsf(du);
    }
    {   // zero a1 pad rows 56..63 (data region)
        int r = 56 + (t >> 5);
        float4 z = {0.f, 0.f, 0.f, 0.f};
        *(float4*)((char*)act + (size_t)r*528 + (size_t)(t & 31)*16) = z;
    }
    __syncthreads();

    // ---- phase 1: decomposed layer-1, packed edge pairs; gate via quad-DPP reduce ----
    {
        const f32x2 wr2  = {wr, wr},  wd2  = {wd, wd},  wa2  = {wa, wa};
        const f32x2 gwr2 = {gwr,gwr}, gwd2 = {gwd,gwd}, gwa2 = {gwa,gwa};
        const f32x2 g22  = {g2, g2};
        float sacc[14];
        const bool p1 = (lane & 1), p2 = ((lane & 2) != 0);
        #pragma unroll
        for (int mq = 0; mq < 14; ++mq) {
            float gq[4];
            #pragma unroll
            for (int pp = 0; pp < 2; ++pp) {
                const int e0 = mq*4 + pp*2, e1 = e0 + 1;
                const int nd0 = e0/7, q0 = nd0 + (e0 - nd0*7);
                const int nd1 = e1/7, q1 = nd1 + (e1 - nd1*7);
                f32x2 rel = *(const f32x2*)&s_rel[e0];
                f32x2 du  = *(const f32x2*)&s_du[e0];
                f32x2 ad  = *(const f32x2*)&s_ad[e0];
                f32x2 pm; pm[0] = pam[nd0] + (bm[q0] + tm); pm[1] = pam[nd1] + (bm[q1] + tm);
                pm = __builtin_elementwise_fma(rel, wr2, pm);
                pm = __builtin_elementwise_fma(du,  wd2, pm);
                pm = __builtin_elementwise_fma(ad,  wa2, pm);
                f32x2 gm = gelu2(pm);
                act[e0*ARS + t] = __float2bfloat16(gm[0]);
                act[e1*ARS + t] = __float2bfloat16(gm[1]);
                f32x2 pg; pg[0] = pag[nd0] + (bg[q0] + tg); pg[1] = pag[nd1] + (bg[q1] + tg);
                pg = __builtin_elementwise_fma(rel, gwr2, pg);
                pg = __builtin_elementwise_fma(du,  gwd2, pg);
                pg = __builtin_elementwise_fma(ad,  gwa2, pg);
                f32x2 gg = gelu2(pg) * g22;
                gq[pp*2] = gg[0]; gq[pp*2+1] = gg[1];
            }
            float xx = p1 ? gq[1] : gq[0], yy = p1 ? gq[0] : gq[1];
            xx += dpp_xor1(yy);
            float zz = p1 ? gq[3] : gq[2], ww = p1 ? gq[2] : gq[3];
            zz += dpp_xor1(ww);
            float uu = p2 ? zz : xx, vv = p2 ? xx : zz;
            uu += dpp_xor2(vv);
            sacc[mq] = uu;
        }
        #pragma unroll
        for (int m = 0; m < 14; ++m) {
            float v = sacc[m];
            v += __shfl_xor(v, 4);
            v += __shfl_xor(v, 8);
            v += __shfl_xor(v, 16);
            v += __shfl_xor(v, 32);
            if (lane < 4) s_gp[wv][m*4 + lane] = v;
        }
    }
    __syncthreads();
    if (t < EEPB)
        s_gate[t] = sigmoid_f(s_gp[0][t] + s_gp[1][t] + s_gp[2][t] + s_gp[3][t] + gate_b2[0]);

    // ---- layer 2: a2 = gelu(a1 @ w2 + b2)  [MFMA 32x32x16 bf16] ----
    const int cl = lane & 31;
    const int g  = lane >> 5;
    f32x16 acc00 = zero16(), acc01 = zero16(), acc10 = zero16(), acc11 = zero16();
    {
        const __hip_bfloat16* w2a = w2t + (size_t)((wv*2+0)*32 + cl)*256 + g*8;
        const __hip_bfloat16* w2b = w2t + (size_t)((wv*2+1)*32 + cl)*256 + g*8;
        const __hip_bfloat16* a1a = act + (size_t)(cl)*ARS + g*8;
        const __hip_bfloat16* a1b = act + (size_t)(32+cl)*ARS + g*8;
        #pragma unroll
        for (int kt = 0; kt < 16; ++kt) {
            bf16x8 bfa = *(const bf16x8*)(w2a + kt*16);
            bf16x8 bfb = *(const bf16x8*)(w2b + kt*16);
            bf16x8 afa = *(const bf16x8*)(a1a + kt*16);
            bf16x8 afb = *(const bf16x8*)(a1b + kt*16);
            acc00 = MFMA32(afa, bfa, acc00);
            acc01 = MFMA32(afa, bfb, acc01);
            acc10 = MFMA32(afb, bfa, acc10);
            acc11 = MFMA32(afb, bfb, acc11);
        }
    }
    __syncthreads();   // all a1 reads done -> safe to overwrite act with a2
    {
        const int c0 = (wv*2+0)*32 + cl;
        const int c1 = (wv*2+1)*32 + cl;
        float b20 = msg_b2[c0], b21 = msg_b2[c1];
        #pragma unroll
        for (int r = 0; r < 16; r += 2) {
            int row0 = (r&3) + 8*(r>>2) + 4*g;     // even; pair rows row0, row0+1
            f32x2 v0 = {acc00[r] + b20, acc00[r+1] + b20};
            f32x2 g0 = gelu2(v0);
            act[row0*ARS + c0]     = __float2bfloat16(g0[0]);
            act[(row0+1)*ARS + c0] = __float2bfloat16(g0[1]);
            f32x2 v1 = {acc01[r] + b21, acc01[r+1] + b21};
            f32x2 g1 = gelu2(v1);
            act[row0*ARS + c1]     = __float2bfloat16(g1[0]);
            act[(row0+1)*ARS + c1] = __float2bfloat16(g1[1]);
            if (r < 12) {   // rows 32+row0 >= 56 are pad: skip
                int row1 = 32 + row0;
                f32x2 v2 = {acc10[r] + b20, acc10[r+1] + b20};
                f32x2 g2v = gelu2(v2);
                act[row1*ARS + c0]     = __float2bfloat16(g2v[0]);
                act[(row1+1)*ARS + c0] = __float2bfloat16(g2v[1]);
                f32x2 v3 = {acc11[r] + b21, acc11[r+1] + b21};
                f32x2 g3 = gelu2(v3);
                act[row1*ARS + c1]     = __float2bfloat16(g3[0]);
                act[(row1+1)*ARS + c1] = __float2bfloat16(g3[1]);
            }
        }
    }
    __syncthreads();   // a2 complete

    // ---- layer 3: msg = (a2 @ w3 + b3) * gate  [MFMA 32x32x16 bf16] ----
    f32x16 m0 = zero16(), m1 = zero16();
    {
        const __hip_bfloat16* w3p = w3t + (size_t)(wv*32 + cl)*256 + g*8;
        const __hip_bfloat16* a2a = act + (size_t)(cl)*ARS + g*8;
        const __hip_bfloat16* a2b = act + (size_t)(32+cl)*ARS + g*8;
        #pragma unroll
        for (int kt = 0; kt < 16; ++kt) {
            bf16x8 bfr = *(const bf16x8*)(w3p + kt*16);
            m0 = MFMA32(*(const bf16x8*)(a2a + kt*16), bfr, m0);
            m1 = MFMA32(*(const bf16x8*)(a2b + kt*16), bfr, m1);
        }
    }
    __syncthreads();   // all a2 reads done -> safe to overwrite act with msgbuf
    float* msgbuf = (float*)act;   // [56][MRS] f32
    {
        const int c = wv*32 + cl;
        float b3v = msg_b3[c];
        #pragma unroll
        for (int r = 0; r < 16; r += 2) {
            int row0 = (r&3) + 8*(r>>2) + 4*g;   // even
            f32x2 mm = {m0[r] + b3v, m0[r+1] + b3v};
            f32x2 gt = {s_gate[row0], s_gate[row0+1]};
            mm *= gt;
            msgbuf[row0*MRS + c]     = mm[0];
            msgbuf[(row0+1)*MRS + c] = mm[1];
            int row1 = 32 + row0;
            if (row1 + 1 < EEPB) {
                f32x2 nn = {m1[r] + b3v, m1[r+1] + b3v};
                f32x2 ht = {s_gate[row1], s_gate[row1+1]};
                nn *= ht;
                msgbuf[row1*MRS + c]     = nn[0];
                msgbuf[(row1+1)*MRS + c] = nn[1];
            }
        }
    }
    __syncthreads();

    // ---- aggregate the 7 edges of each node (packed col-pairs, bf16 out) ----
    {
        const int c2  = (t & 63) * 2;
        const int grp = t >> 6;
        #pragma unroll
        for (int p = 0; p < 2; ++p) {
            int nd = grp + p*4;
            f32x2 s = {0.f, 0.f};
            #pragma unroll
            for (int q2 = 0; q2 < 7; ++q2)
                s += *(const f32x2*)&msgbuf[(nd*7+q2)*MRS + c2];
            ushort2 u;
            u.x = (unsigned short)f2bs(s[0]);
            u.y = (unsigned short)f2bs(s[1]);
            *(ushort2*)&AGG[(size_t)(base+nd)*128 + c2] = u;
        }
    }
}

// ---------------- update kernel (MFMA, M=32): u1 (incl h-part), u2, u3 + local + final gelu ----------------
#define UM 32

__global__ __launch_bounds__(256, 4)
void update_kernel(const __hip_bfloat16* __restrict__ w1ut, const __hip_bfloat16* __restrict__ w2ut,
                   const __hip_bfloat16* __restrict__ w3ut, const __hip_bfloat16* __restrict__ wwt,
                   const float* __restrict__ upd_b2, const float* __restrict__ upd_b3,
                   const float* __restrict__ W_b,
                   const float* __restrict__ h, const __hip_bfloat16* __restrict__ AGG,
                   const float* __restrict__ TU,
                   float* __restrict__ out)
{
    __shared__ __align__(16) __hip_bfloat16 ub[UM*ARS];   // [h|agg] -> u1 -> u2, in place
    const int t = threadIdx.x;
    const int lane = t & 63, wv = t >> 6;
    const int cl = lane & 31, g = lane >> 5;
    const int base = blockIdx.x * UM;
    const int b = base >> 12;

    #pragma unroll
    for (int i = 0; i < 4; ++i) {          // stage h tile (32 x 128 f32 -> bf16)
        int f = (i*256 + t)*4;
        int row = f >> 7, col = f & 127;
        float4 hv = *(const float4*)&h[(size_t)base*128 + f];
        s16x4 pk; pk[0]=f2bs(hv.x); pk[1]=f2bs(hv.y); pk[2]=f2bs(hv.z); pk[3]=f2bs(hv.w);
        *(s16x4*)&ub[row*ARS + col] = pk;
    }
    #pragma unroll
    for (int i = 0; i < 2; ++i) {          // stage AGG tile (32 x 128 bf16, direct copy)
        int idx = i*256 + t;               // 32 rows x 16 chunks of 8 bf16
        int row = idx >> 4, ch = idx & 15;
        *(float4*)&ub[row*ARS + 128 + ch*8] =
            *(const float4*)&AGG[(size_t)(base+row)*128 + ch*8];
    }
    __syncthreads();

    // ---- u1 = gelu([h|agg] @ upd_w1[0:256] + TU)  K=256, N=256 ----
    // ---- also HL = h @ W_w (K=128, N=128), kept in registers ----
    f32x16 u0a = zero16(), u1a = zero16(), hl = zero16();
    {
        const __hip_bfloat16* a0 = ub + (size_t)(cl)*ARS + g*8;
        const __hip_bfloat16* b0 = w1ut + (size_t)(wv*64 + cl)*256 + g*8;
        const __hip_bfloat16* b1 = w1ut + (size_t)(wv*64 + 32 + cl)*256 + g*8;
        const __hip_bfloat16* bw = wwt + (size_t)(wv*32 + cl)*128 + g*8;
        #pragma unroll
        for (int kt = 0; kt < 16; ++kt) {
            bf16x8 af = *(const bf16x8*)(a0 + kt*16);
            u0a = MFMA32(af, *(const bf16x8*)(b0 + kt*16), u0a);
            u1a = MFMA32(af, *(const bf16x8*)(b1 + kt*16), u1a);
            if (kt < 8)
                hl = MFMA32(af, *(const bf16x8*)(bw + kt*16), hl);
        }
    }
    __syncthreads();   // staging reads done
    {
        const int c0 = wv*64 + cl, c1 = c0 + 32;
        float tu0 = TU[b*256 + c0], tu1 = TU[b*256 + c1];
        #pragma unroll
        for (int r = 0; r < 16; r += 2) {
            int row = (r&3) + 8*(r>>2) + 4*g;
            f32x2 v0 = {u0a[r] + tu0, u0a[r+1] + tu0};
            f32x2 g0 = gelu2(v0);
            ub[row*ARS + c0]     = __float2bfloat16(g0[0]);
            ub[(row+1)*ARS + c0] = __float2bfloat16(g0[1]);
            f32x2 v1 = {u1a[r] + tu1, u1a[r+1] + tu1};
            f32x2 g1 = gelu2(v1);
            ub[row*ARS + c1]     = __float2bfloat16(g1[0]);
            ub[(row+1)*ARS + c1] = __float2bfloat16(g1[1]);
        }
    }
    __syncthreads();

    // ---- u2 = gelu(u1 @ w2u + b2)  K=256, N=256 ----
    f32x16 v0a = zero16(), v1a = zero16();
    {
        const __hip_bfloat16* a0 = ub + (size_t)(cl)*ARS + g*8;
        const __hip_bfloat16* b0 = w2ut + (size_t)(wv*64 + cl)*256 + g*8;
        const __hip_bfloat16* b1 = w2ut + (size_t)(wv*64 + 32 + cl)*256 + g*8;
        #pragma unroll
        for (int kt = 0; kt < 16; ++kt) {
            bf16x8 af = *(const bf16x8*)(a0 + kt*16);
            v0a = MFMA32(af, *(const bf16x8*)(b0 + kt*16), v0a);
            v1a = MFMA32(af, *(const bf16x8*)(b1 + kt*16), v1a);
        }
    }
    __syncthreads();   // u1 reads done
    {
        const int c0 = wv*64 + cl, c1 = c0 + 32;
        float b20 = upd_b2[c0], b21 = upd_b2[c1];
        #pragma unroll
        for (int r = 0; r < 16; r += 2) {
            int row = (r&3) + 8*(r>>2) + 4*g;
            f32x2 v0 = {v0a[r] + b20, v0a[r+1] + b20};
            f32x2 g0 = gelu2(v0);
            ub[row*ARS + c0]     = __float2bfloat16(g0[0]);
            ub[(row+1)*ARS + c0] = __float2bfloat16(g0[1]);
            f32x2 v1 = {v1a[r] + b21, v1a[r+1] + b21};
            f32x2 g1 = gelu2(v1);
            ub[row*ARS + c1]     = __float2bfloat16(g1[0]);
            ub[(row+1)*ARS + c1] = __float2bfloat16(g1[1]);
        }
    }
    __syncthreads();

    // ---- out = gelu(u2 @ w3u + b3 + HL + W_b)  K=256, N=128 ----
    f32x16 w0a = zero16();
    {
        const __hip_bfloat16* wp = w3ut + (size_t)(wv*32 + cl)*256 + g*8;
        const __hip_bfloat16* a0 = ub + (size_t)(cl)*ARS + g*8;
        #pragma unroll
        for (int kt = 0; kt < 16; ++kt)
            w0a = MFMA32(*(const bf16x8*)(a0 + kt*16), *(const bf16x8*)(wp + kt*16), w0a);
    }
    {
        const int c = wv*32 + cl;
        float b3v = upd_b3[c] + W_b[c];
        #pragma unroll
        for (int r = 0; r < 16; r += 2) {
            int row = (r&3) + 8*(r>>2) + 4*g;
            f32x2 vv = {w0a[r] + b3v + hl[r], w0a[r+1] + b3v + hl[r+1]};
            f32x2 gg = gelu2(vv);
            size_t o0 = (size_t)(base+row)*128 + c;
            size_t o1 = (size_t)(base+row+1)*128 + c;
            out[o0] = gg[0];
            out[o1] = gg[1];
        }
    }
}

// ---------------- launch ----------------
extern "C" void kernel_launch(void* const* d_in, const int* in_sizes, int n_in,
                              void* d_out, int out_size, void* d_ws, size_t ws_size,
                              hipStream_t stream)
{
    const float* h      = (const float*)d_in[0];
    const float* x      = (const float*)d_in[1];
    const float* tau    = (const float*)d_in[2];
    const float* u0     = (const float*)d_in[3];
    const float* msg_w1 = (const float*)d_in[4];
    const float* msg_b1 = (const float*)d_in[5];
    const float* msg_w2 = (const float*)d_in[6];
    const float* msg_b2 = (const float*)d_in[7];
    const float* msg_w3 = (const float*)d_in[8];
    const float* msg_b3 = (const float*)d_in[9];
    const float* gate_w1= (const float*)d_in[10];
    const float* gate_b1= (const float*)d_in[11];
    const float* gate_w2= (const float*)d_in[12];
    const float* gate_b2= (const float*)d_in[13];
    const float* upd_w1 = (const float*)d_in[14];
    const float* upd_b1 = (const float*)d_in[15];
    const float* upd_w2 = (const float*)d_in[16];
    const float* upd_b2 = (const float*)d_in[17];
    const float* upd_w3 = (const float*)d_in[18];
    const float* upd_b3 = (const float*)d_in[19];
    const float* W_w    = (const float*)d_in[20];
    const float* W_b    = (const float*)d_in[21];
    float* out = (float*)d_out;

    char* ws = (char*)d_ws;
    size_t off = 0;
    auto alloc = [&](size_t bytes) -> void* {
        void* p = ws + off;
        off += (bytes + 255) & ~(size_t)255;
        return p;
    };
    __hip_bfloat16* PAm = (__hip_bfloat16*)alloc((size_t)NNODES*256*2);
    __hip_bfloat16* PBm = (__hip_bfloat16*)alloc((size_t)NNODES*256*2);
    __hip_bfloat16* PAg = (__hip_bfloat16*)alloc((size_t)NNODES*256*2);
    __hip_bfloat16* PBg = (__hip_bfloat16*)alloc((size_t)NNODES*256*2);
    __hip_bfloat16* AGG = (__hip_bfloat16*)alloc((size_t)NNODES*128*2);
    float* TM  = (float*)alloc(8*256*4);
    float* TG  = (float*)alloc(8*256*4);
    float* TU  = (float*)alloc(8*256*4);
    __hip_bfloat16* w2t   = (__hip_bfloat16*)alloc((size_t)256*256*2);
    __hip_bfloat16* w3t   = (__hip_bfloat16*)alloc((size_t)128*256*2);
    __hip_bfloat16* wall_t= (__hip_bfloat16*)alloc((size_t)1024*128*2);
    __hip_bfloat16* w1ut  = (__hip_bfloat16*)alloc((size_t)256*256*2);
    __hip_bfloat16* w2ut  = (__hip_bfloat16*)alloc((size_t)256*256*2);
    __hip_bfloat16* w3ut  = (__hip_bfloat16*)alloc((size_t)128*256*2);
    __hip_bfloat16* wwt   = (__hip_bfloat16*)alloc((size_t)128*128*2);
    (void)ws_size; (void)in_sizes; (void)n_in; (void)out_size;

    wconv_kernel<<<1608, 256, 0, stream>>>(msg_w2, msg_w3, msg_w1, gate_w1,
                                           upd_w1, upd_w2, upd_w3, W_w,
                                           tau, msg_b1, gate_b1, upd_b1,
                                           w2t, w3t, wall_t, w1ut, w2ut, w3ut, wwt,
                                           TM, TG, TU);
    precompute_kernel<<<NNODES/64, 256, 0, stream>>>(h, wall_t,
                                                     PAm, PBm, PAg, PBg);
    edge_kernel<<<NNODES/ENPB, 256, 0, stream>>>(x, u0, msg_w1, gate_w1,
                                                 w2t, msg_b2, w3t, msg_b3,
                                                 gate_w2, gate_b2,
                                                 PAm, PBm, PAg, PBg, TM, TG, AGG);
    update_kernel<<<NNODES/UM, 256, 0, stream>>>(w1ut, w2ut, w3ut, wwt,
                                                 upd_b2, upd_b3, W_b,
                                                 h, AGG, TU, out);
}